// Round 12
// baseline (237.650 us; speedup 1.0000x reference)
//
#include <hip/hip_runtime.h>

typedef float f32x4 __attribute__((ext_vector_type(4)));
typedef _Float16 half2_t __attribute__((ext_vector_type(2)));
typedef _Float16 half4_t __attribute__((ext_vector_type(4)));
typedef _Float16 half8_t __attribute__((ext_vector_type(8)));

// ================= CSR build via 2-level counting sort =================
// Edges packed as (dst<<16)|src (n <= 65536). Coarse bin = dst>>7.
#define CSR_CHUNK 4096

// Per-chunk histogram (non-atomic global writes) fused with W fp16 hi/lo splits.
__global__ __launch_bounds__(256) void k_bh_ws(
    const int* __restrict__ dst, int* __restrict__ gh, int e, int nbin, int nchunk,
    const float* __restrict__ W1, const float* __restrict__ W2, const float* __restrict__ W3,
    _Float16* __restrict__ w1h, _Float16* __restrict__ w1l,
    _Float16* __restrict__ w2h, _Float16* __restrict__ w2l,
    _Float16* __restrict__ w3h, _Float16* __restrict__ w3l)
{
    __shared__ int lh[512];
    const int bid = blockIdx.x;
    if (bid < nchunk) {
        for (int i = threadIdx.x; i < nbin; i += 256) lh[i] = 0;
        __syncthreads();
        int lo = bid * CSR_CHUNK;
        int hi = min(lo + CSR_CHUNK, e);
        for (int i = lo + threadIdx.x; i < hi; i += 256)
            atomicAdd(&lh[dst[i] >> 7], 1);
        __syncthreads();
        for (int i = threadIdx.x; i < nbin; i += 256)
            gh[bid * 512 + i] = lh[i];
    } else {
        const int N1 = 128 * 128, N2 = 128 * 128, N3 = 64 * 128;
        const int nb = gridDim.x - nchunk;
        for (int i = (bid - nchunk) * 256 + threadIdx.x; i < N1 + N2 + N3; i += nb * 256) {
            const float* W; _Float16 *ph, *pl; int j;
            if (i < N1)           { W = W1; ph = w1h; pl = w1l; j = i; }
            else if (i < N1 + N2) { W = W2; ph = w2h; pl = w2l; j = i - N1; }
            else                  { W = W3; ph = w3h; pl = w3l; j = i - N1 - N2; }
            float v = W[j];
            _Float16 h = (_Float16)v;
            ph[j] = h;
            pl[j] = (_Float16)(v - (float)h);
        }
    }
}

__global__ __launch_bounds__(512) void k_bscan(
    const int* __restrict__ gh, int* __restrict__ binstart, int* __restrict__ bincur,
    int* __restrict__ rowst, int e, int nbin, int nchunk, int n)
{
    int tid = threadIdx.x, lane = tid & 63, wv = tid >> 6;
    __shared__ int ws[8];
    int x = 0;
    if (tid < nbin)
        for (int c = 0; c < nchunk; c++) x += gh[c * 512 + tid];
    int v = x;
#pragma unroll
    for (int off = 1; off < 64; off <<= 1) {
        int t = __shfl_up(v, off, 64);
        if (lane >= off) v += t;
    }
    if (lane == 63) ws[wv] = v;
    __syncthreads();
    if (wv == 0) {
        int w = (lane < 8) ? ws[lane] : 0;
#pragma unroll
        for (int off = 1; off < 8; off <<= 1) {
            int t = __shfl_up(w, off, 64);
            if (lane >= off) w += t;
        }
        if (lane < 8) ws[lane] = w;
    }
    __syncthreads();
    if (wv > 0) v += ws[wv - 1];
    int excl = v - x;
    if (tid < nbin) { binstart[tid] = excl; bincur[tid] = excl; }
    if (tid == 0) { binstart[nbin] = e; rowst[n] = e; }
}

__global__ __launch_bounds__(256) void k_scatter(
    const int* __restrict__ src, const int* __restrict__ dst,
    int* __restrict__ bincur, unsigned* __restrict__ sorted, int e, int nbin)
{
    __shared__ unsigned st[CSR_CHUNK];
    __shared__ int lh[512];
    __shared__ int base[512];
    for (int i = threadIdx.x; i < nbin; i += 256) lh[i] = 0;
    __syncthreads();
    int lo = blockIdx.x * CSR_CHUNK;
    int cnt = min(lo + CSR_CHUNK, e) - lo;
    for (int i = threadIdx.x; i < cnt; i += 256) {
        int d = dst[lo + i], s = src[lo + i];
        st[i] = ((unsigned)d << 16) | (unsigned)s;
        atomicAdd(&lh[d >> 7], 1);
    }
    __syncthreads();
    for (int i = threadIdx.x; i < nbin; i += 256) {
        int c = lh[i];
        base[i] = c ? atomicAdd(&bincur[i], c) : 0;
        lh[i] = 0;
    }
    __syncthreads();
    for (int i = threadIdx.x; i < cnt; i += 256) {
        unsigned u = st[i];
        int b = (int)(u >> 23);
        int r = atomicAdd(&lh[b], 1);
        sorted[base[b] + r] = u;
    }
}

__global__ __launch_bounds__(256) void k_fine(
    const unsigned* __restrict__ sorted, const int* __restrict__ binstart,
    int* __restrict__ rowst, int* __restrict__ csrc, int n)
{
    int b = blockIdx.x;
    int s = binstart[b], t = binstart[b + 1];
    __shared__ int fh[128], fex[128], fcur[128];
    __shared__ int wtot;
    int tid = threadIdx.x;
    if (tid < 128) fh[tid] = 0;
    __syncthreads();
    for (int i = s + tid; i < t; i += 256)
        atomicAdd(&fh[(sorted[i] >> 16) & 127], 1);
    __syncthreads();
    if (tid < 128) {
        int lane = tid & 63;
        int x = fh[tid];
        int v = x;
#pragma unroll
        for (int off = 1; off < 64; off <<= 1) {
            int tv = __shfl_up(v, off, 64);
            if (lane >= off) v += tv;
        }
        fex[tid] = v - x;
        if (tid == 63) wtot = v;
    }
    __syncthreads();
    if (tid >= 64 && tid < 128) fex[tid] += wtot;
    __syncthreads();
    if (tid < 128) {
        int node = b * 128 + tid;
        if (node < n) rowst[node] = s + fex[tid];
        fcur[tid] = 0;
    }
    __syncthreads();
    for (int i = s + tid; i < t; i += 256) {
        unsigned u = sorted[i];
        int d = (u >> 16) & 127;
        int r = atomicAdd(&fcur[d], 1);
        csrc[s + fex[d] + r] = (int)(u & 0xFFFFu);
    }
}

// ---------------- MFMA Linear: W fragments REGISTER-resident, col-split ----------------
// R11 lesson: LDS-staged W (64KB) capped occupancy (VGPR 216, occ 8%, 44us,
// MfmaUtil 2.5%) -- latency-bound, not ds-bound. Now: each of 4 waves owns
// DOUT/4 output cols; its hi/lo W fragments live in 64 (NTW=2) / 32 (NTW=1)
// VGPRs, loaded once per block. Hot loop: X loads + 16 MFMA from regs.
// Row-norm combined across waves via 256B LDS (2 barriers/group, uniform).
template <int DOUT, bool F32IN>
__global__ __launch_bounds__(256) void k_linear_mfma(
    const void* __restrict__ Xv, const _Float16* __restrict__ Whf,
    const _Float16* __restrict__ Wlf, const float* __restrict__ B,
    _Float16* __restrict__ Hn, float* __restrict__ nrm, float* __restrict__ exself, int n)
{
    constexpr int NTW = DOUT / 64;   // tiles per wave (2 for DOUT=128, 1 for 64)
    const int tid = threadIdx.x;
    const int w = tid >> 6;
    const int lane = tid & 63;
    const int r16 = lane & 15, kh = lane >> 4;

    // one-time: this wave's W fragments -> registers (B[k][col] = W[col][k])
    half8_t wh[NTW][4], wl[NTW][4];
    float bs[NTW];
#pragma unroll
    for (int tt = 0; tt < NTW; tt++) {
        const int col = (w * NTW + tt) * 16 + r16;
        bs[tt] = B[col];
#pragma unroll
        for (int ks = 0; ks < 4; ks++) {
            wh[tt][ks] = *reinterpret_cast<const half8_t*>(Whf + (size_t)col * 128 + ks * 32 + kh * 8);
            wl[tt][ks] = *reinterpret_cast<const half8_t*>(Wlf + (size_t)col * 128 + ks * 32 + kh * 8);
        }
    }

    __shared__ float sM[4][16];
    const int nu = (n + 15) >> 4;
    const float* Xf32 = (const float*)Xv;
    const _Float16* Xf16 = (const _Float16*)Xv;

    for (int u = blockIdx.x; u < nu; u += gridDim.x) {
        const int rg = u << 4;
        half8_t a[4];
        if (F32IN) {
            const float* px = Xf32 + (size_t)(rg + r16) * 128 + kh * 8;
#pragma unroll
            for (int ks = 0; ks < 4; ks++) {
                float4 xa = *reinterpret_cast<const float4*>(px + ks * 32);
                float4 xb = *reinterpret_cast<const float4*>(px + ks * 32 + 4);
                a[ks] = (half8_t){(_Float16)xa.x, (_Float16)xa.y, (_Float16)xa.z, (_Float16)xa.w,
                                  (_Float16)xb.x, (_Float16)xb.y, (_Float16)xb.z, (_Float16)xb.w};
            }
        } else {
            const _Float16* px = Xf16 + (size_t)(rg + r16) * 128 + kh * 8;
#pragma unroll
            for (int ks = 0; ks < 4; ks++)
                a[ks] = *reinterpret_cast<const half8_t*>(px + ks * 32);
        }

        f32x4 acc[NTW];
#pragma unroll
        for (int tt = 0; tt < NTW; tt++) acc[tt] = (f32x4){0.f, 0.f, 0.f, 0.f};
#pragma unroll
        for (int ks = 0; ks < 4; ks++) {
#pragma unroll
            for (int tt = 0; tt < NTW; tt++) {
                acc[tt] = __builtin_amdgcn_mfma_f32_16x16x32_f16(a[ks], wh[tt][ks], acc[tt], 0, 0, 0);
                acc[tt] = __builtin_amdgcn_mfma_f32_16x16x32_f16(a[ks], wl[tt][ks], acc[tt], 0, 0, 0);
            }
        }

        // bias + partial sum-of-squares (this wave's cols)
        float ss[4] = {0.f, 0.f, 0.f, 0.f};
#pragma unroll
        for (int tt = 0; tt < NTW; tt++) {
#pragma unroll
            for (int r = 0; r < 4; r++) {
                float v = acc[tt][r] + bs[tt];
                acc[tt][r] = v;
                ss[r] += v * v;
            }
        }
#pragma unroll
        for (int m = 8; m > 0; m >>= 1) {
#pragma unroll
            for (int r = 0; r < 4; r++) ss[r] += __shfl_xor(ss[r], m, 64);
        }
        // cross-wave norm combine (rows kh*4+r)
        if (r16 == 0) {
#pragma unroll
            for (int r = 0; r < 4; r++) sM[w][kh * 4 + r] = ss[r];
        }
        __syncthreads();
        float riv[4], nrmv[4];
#pragma unroll
        for (int r = 0; r < 4; r++) {
            float tot = sM[0][kh * 4 + r] + sM[1][kh * 4 + r] +
                        sM[2][kh * 4 + r] + sM[3][kh * 4 + r];
            nrmv[r] = sqrtf(tot);
            riv[r] = 1.0f / fmaxf(nrmv[r], 1e-12f);
        }
        __syncthreads();   // sM reusable next iteration

#pragma unroll
        for (int tt = 0; tt < NTW; tt++) {
            const int col = (w * NTW + tt) * 16 + r16;
#pragma unroll
            for (int r = 0; r < 4; r++) {
                int grow = rg + kh * 4 + r;
                if (grow < n)
                    Hn[(size_t)grow * DOUT + col] = (_Float16)(acc[tt][r] * riv[r]);
            }
        }
        if (w == 0 && r16 == 0) {
#pragma unroll
            for (int r = 0; r < 4; r++) {
                int grow = rg + kh * 4 + r;
                if (grow < n) {
                    float sc = nrmv[r] * riv[r];
                    nrm[grow] = nrmv[r];
                    exself[grow] = __expf(sc * sc);
                }
            }
        }
    }
}

// ---------------- Fused attention aggregation (fp16 rows, SW-pipelined) ----------------
__global__ __launch_bounds__(256) void k_agg128(
    const _Float16* __restrict__ Hn, const float* __restrict__ nrm, const float* __restrict__ exself,
    const int* __restrict__ rowst, const int* __restrict__ csrc,
    _Float16* __restrict__ Oxf, int n)
{
    const int wave = threadIdx.x >> 6, lane = threadIdx.x & 63;
    const int node = blockIdx.x * 4 + wave;
    if (node >= n) return;
    const int g = lane >> 4;
    const int t = lane & 15;

    half8_t hv = *reinterpret_cast<const half8_t*>(Hn + (size_t)node * 128 + t * 8);
    half2_t h2[4];
#pragma unroll
    for (int j = 0; j < 4; j++) h2[j] = (half2_t){hv[2 * j], hv[2 * j + 1]};
    float es = exself[node];
    float esn = es * nrm[node];
    float acc[8];
    float denom;
    if (g == 0) {
#pragma unroll
        for (int j = 0; j < 8; j++) acc[j] = esn * (float)hv[j];
        denom = es;
    } else {
#pragma unroll
        for (int j = 0; j < 8; j++) acc[j] = 0.f;
        denom = 0.f;
    }

    const int p0 = rowst[node], p1 = rowst[node + 1];
    const int nit = (p1 - p0 + 7) >> 3;

    bool vA0 = false, vB0 = false;
    half8_t av0, bv0;
    float nA0 = 0.f, nB0 = 0.f;
    if (nit > 0) {
        int pA = p0 + g, pB = pA + 4;
        vA0 = pA < p1; vB0 = pB < p1;
        int sA = vA0 ? csrc[pA] : node;
        int sB = vB0 ? csrc[pB] : node;
        av0 = *reinterpret_cast<const half8_t*>(Hn + (size_t)sA * 128 + t * 8);
        bv0 = *reinterpret_cast<const half8_t*>(Hn + (size_t)sB * 128 + t * 8);
        nA0 = nrm[sA]; nB0 = nrm[sB];
    }

    for (int k = 0; k < nit; k++) {
        bool vA1 = false, vB1 = false;
        half8_t av1, bv1;
        float nA1 = 0.f, nB1 = 0.f;
        if (k + 1 < nit) {
            int pA = p0 + (k + 1) * 8 + g, pB = pA + 4;
            vA1 = pA < p1; vB1 = pB < p1;
            int sA = vA1 ? csrc[pA] : node;
            int sB = vB1 ? csrc[pB] : node;
            av1 = *reinterpret_cast<const half8_t*>(Hn + (size_t)sA * 128 + t * 8);
            bv1 = *reinterpret_cast<const half8_t*>(Hn + (size_t)sB * 128 + t * 8);
            nA1 = nrm[sA]; nB1 = nrm[sB];
        }

        half2_t da2 = (half2_t){hv[0], hv[1]} * (half2_t){av0[0], av0[1]};
        half2_t db2 = (half2_t){hv[0], hv[1]} * (half2_t){bv0[0], bv0[1]};
#pragma unroll
        for (int j = 1; j < 4; j++) {
            da2 += h2[j] * (half2_t){av0[2 * j], av0[2 * j + 1]};
            db2 += h2[j] * (half2_t){bv0[2 * j], bv0[2 * j + 1]};
        }
        float dA = (float)da2[0] + (float)da2[1];
        float dB = (float)db2[0] + (float)db2[1];
#pragma unroll
        for (int m = 8; m > 0; m >>= 1) {
            dA += __shfl_xor(dA, m, 64);
            dB += __shfl_xor(dB, m, 64);
        }
        float exA = vA0 ? __expf(dA) : 0.f;
        float exB = vB0 ? __expf(dB) : 0.f;
        denom += exA + exB;
        float wA = exA * nA0, wB = exB * nB0;
#pragma unroll
        for (int j = 0; j < 8; j++) acc[j] += wA * (float)av0[j] + wB * (float)bv0[j];

        vA0 = vA1; vB0 = vB1; av0 = av1; bv0 = bv1; nA0 = nA1; nB0 = nB1;
    }

#pragma unroll
    for (int j = 0; j < 8; j++) {
        acc[j] += __shfl_xor(acc[j], 16, 64);
        acc[j] += __shfl_xor(acc[j], 32, 64);
    }
    denom += __shfl_xor(denom, 16, 64);
    denom += __shfl_xor(denom, 32, 64);

    if (g == 0) {
        float inv = 1.0f / denom;
        half8_t o;
#pragma unroll
        for (int j = 0; j < 8; j++)
            o[j] = (_Float16)fmaxf(acc[j] * inv, 0.f);
        *reinterpret_cast<half8_t*>(Oxf + (size_t)node * 128 + t * 8) = o;
    }
}

__global__ __launch_bounds__(256) void k_agg64_lsm(
    const _Float16* __restrict__ Hn, const float* __restrict__ nrm, const float* __restrict__ exself,
    const int* __restrict__ rowst, const int* __restrict__ csrc,
    float* __restrict__ OUT, int n)
{
    const int wave = threadIdx.x >> 6, lane = threadIdx.x & 63;
    const int node = blockIdx.x * 4 + wave;
    if (node >= n) return;
    const int g = lane >> 4;
    const int t = lane & 15;

    half4_t hv = *reinterpret_cast<const half4_t*>(Hn + (size_t)node * 64 + t * 4);
    half2_t h2[2] = {(half2_t){hv[0], hv[1]}, (half2_t){hv[2], hv[3]}};
    float es = exself[node];
    float esn = es * nrm[node];
    float acc[4];
    float denom;
    if (g == 0) {
#pragma unroll
        for (int j = 0; j < 4; j++) acc[j] = esn * (float)hv[j];
        denom = es;
    } else {
        acc[0] = acc[1] = acc[2] = acc[3] = 0.f;
        denom = 0.f;
    }

    const int p0 = rowst[node], p1 = rowst[node + 1];
    const int nit = (p1 - p0 + 7) >> 3;

    bool vA0 = false, vB0 = false;
    half4_t av0, bv0;
    float nA0 = 0.f, nB0 = 0.f;
    if (nit > 0) {
        int pA = p0 + g, pB = pA + 4;
        vA0 = pA < p1; vB0 = pB < p1;
        int sA = vA0 ? csrc[pA] : node;
        int sB = vB0 ? csrc[pB] : node;
        av0 = *reinterpret_cast<const half4_t*>(Hn + (size_t)sA * 64 + t * 4);
        bv0 = *reinterpret_cast<const half4_t*>(Hn + (size_t)sB * 64 + t * 4);
        nA0 = nrm[sA]; nB0 = nrm[sB];
    }

    for (int k = 0; k < nit; k++) {
        bool vA1 = false, vB1 = false;
        half4_t av1, bv1;
        float nA1 = 0.f, nB1 = 0.f;
        if (k + 1 < nit) {
            int pA = p0 + (k + 1) * 8 + g, pB = pA + 4;
            vA1 = pA < p1; vB1 = pB < p1;
            int sA = vA1 ? csrc[pA] : node;
            int sB = vB1 ? csrc[pB] : node;
            av1 = *reinterpret_cast<const half4_t*>(Hn + (size_t)sA * 64 + t * 4);
            bv1 = *reinterpret_cast<const half4_t*>(Hn + (size_t)sB * 64 + t * 4);
            nA1 = nrm[sA]; nB1 = nrm[sB];
        }

        half2_t da2 = h2[0] * (half2_t){av0[0], av0[1]};
        half2_t db2 = h2[0] * (half2_t){bv0[0], bv0[1]};
        da2 += h2[1] * (half2_t){av0[2], av0[3]};
        db2 += h2[1] * (half2_t){bv0[2], bv0[3]};
        float dA = (float)da2[0] + (float)da2[1];
        float dB = (float)db2[0] + (float)db2[1];
#pragma unroll
        for (int m = 8; m > 0; m >>= 1) {
            dA += __shfl_xor(dA, m, 64);
            dB += __shfl_xor(dB, m, 64);
        }
        float exA = vA0 ? __expf(dA) : 0.f;
        float exB = vB0 ? __expf(dB) : 0.f;
        denom += exA + exB;
        float wA = exA * nA0, wB = exB * nB0;
#pragma unroll
        for (int j = 0; j < 4; j++) acc[j] += wA * (float)av0[j] + wB * (float)bv0[j];

        vA0 = vA1; vB0 = vB1; av0 = av1; bv0 = bv1; nA0 = nA1; nB0 = nB1;
    }

#pragma unroll
    for (int j = 0; j < 4; j++) {
        acc[j] += __shfl_xor(acc[j], 16, 64);
        acc[j] += __shfl_xor(acc[j], 32, 64);
    }
    denom += __shfl_xor(denom, 16, 64);
    denom += __shfl_xor(denom, 32, 64);

    float inv = 1.0f / denom;
    float v0 = acc[0] * inv, v1 = acc[1] * inv, v2 = acc[2] * inv, v3 = acc[3] * inv;
    float mx = fmaxf(fmaxf(v0, v1), fmaxf(v2, v3));
#pragma unroll
    for (int m = 8; m > 0; m >>= 1) mx = fmaxf(mx, __shfl_xor(mx, m, 64));
    float se = __expf(v0 - mx) + __expf(v1 - mx) + __expf(v2 - mx) + __expf(v3 - mx);
#pragma unroll
    for (int m = 8; m > 0; m >>= 1) se += __shfl_xor(se, m, 64);
    float lse = mx + logf(se);
    if (g == 0) {
        float* op = OUT + (size_t)node * 64 + t * 4;
        *reinterpret_cast<float4*>(op) = make_float4(v0 - lse, v1 - lse, v2 - lse, v3 - lse);
    }
}

extern "C" void kernel_launch(void* const* d_in, const int* in_sizes, int n_in,
                              void* d_out, int out_size, void* d_ws, size_t ws_size,
                              hipStream_t stream)
{
    const float* x  = (const float*)d_in[0];
    const int*   ei = (const int*)d_in[1];
    const float* W1 = (const float*)d_in[2];
    const float* b1 = (const float*)d_in[3];
    const float* W2 = (const float*)d_in[4];
    const float* b2 = (const float*)d_in[5];
    const float* W3 = (const float*)d_in[6];
    const float* b3 = (const float*)d_in[7];
    float* out = (float*)d_out;

    const int n = in_sizes[0] / 128;
    const int e = in_sizes[1] / 2;
    const int* esrc = ei;
    const int* edst = ei + e;
    const int npad = (n + 31) & ~31;

    const int nbin = (n + 127) >> 7;
    const int nchunk = (e + CSR_CHUNK - 1) / CSR_CHUNK;

    uintptr_t wp = ((uintptr_t)d_ws + 15) & ~(uintptr_t)15;
#define CARVE(ty, name, count) ty* name = (ty*)wp; wp = (wp + (size_t)(count) * sizeof(ty) + 15) & ~(uintptr_t)15
    CARVE(_Float16, xf, (size_t)npad * 128);
    CARVE(_Float16, hn16, (size_t)npad * 128);
    CARVE(float, nrm, n);
    CARVE(float, exs, n);
    CARVE(int, rowst, n + 1);
    CARVE(int, gh, (size_t)nchunk * 512);
    CARVE(int, binstart, 513);
    CARVE(int, bincur, 512);
    CARVE(unsigned, sorted, e);
    CARVE(int, csrc, e);
    CARVE(_Float16, w1h, 128 * 128);
    CARVE(_Float16, w1l, 128 * 128);
    CARVE(_Float16, w2h, 128 * 128);
    CARVE(_Float16, w2l, 128 * 128);
    CARVE(_Float16, w3h, 64 * 128);
    CARVE(_Float16, w3l, 64 * 128);
#undef CARVE

    k_bh_ws<<<nchunk + 96, 256, 0, stream>>>(edst, gh, e, nbin, nchunk,
                                             W1, W2, W3, w1h, w1l, w2h, w2l, w3h, w3l);
    k_bscan<<<1, 512, 0, stream>>>(gh, binstart, bincur, rowst, e, nbin, nchunk, n);
    k_scatter<<<nchunk, 256, 0, stream>>>(esrc, edst, bincur, sorted, e, nbin);
    k_fine<<<nbin, 256, 0, stream>>>(sorted, binstart, rowst, csrc, n);

    const int nu = (n + 15) / 16;
    const int lgrid = min(nu, 1024);
    const int agrid = (n + 3) / 4;

    k_linear_mfma<128, true><<<lgrid, 256, 0, stream>>>(x, w1h, w1l, b1, hn16, nrm, exs, n);
    k_agg128<<<agrid, 256, 0, stream>>>(hn16, nrm, exs, rowst, csrc, xf, n);
    k_linear_mfma<128, false><<<lgrid, 256, 0, stream>>>(xf, w2h, w2l, b2, hn16, nrm, exs, n);
    k_agg128<<<agrid, 256, 0, stream>>>(hn16, nrm, exs, rowst, csrc, xf, n);
    k_linear_mfma<64, false><<<lgrid, 256, 0, stream>>>(xf, w3h, w3l, b3, hn16, nrm, exs, n);
    k_agg64_lsm<<<agrid, 256, 0, stream>>>(hn16, nrm, exs, rowst, csrc, out, n);
}

// Round 13
// 211.970 us; speedup vs baseline: 1.1211x; 1.1211x over previous
//
#include <hip/hip_runtime.h>

typedef float f32x4 __attribute__((ext_vector_type(4)));
typedef _Float16 half2_t __attribute__((ext_vector_type(2)));
typedef _Float16 half4_t __attribute__((ext_vector_type(4)));
typedef _Float16 half8_t __attribute__((ext_vector_type(8)));

// ================= CSR build via 2-level counting sort =================
// Edges packed as (dst<<16)|src (n <= 65536). Coarse bin = dst>>7.
// NOTE (R12): keep THIS CSR variant. The R11 "per-chunk hist + fused wsplit"
// rework made k_bscan a 196-iteration serial reduction in one block (~16us
// latency) and regressed the total. Single-read bscan + tiny memset is faster.
#define CSR_CHUNK 4096

__global__ __launch_bounds__(256) void k_bh(const int* __restrict__ dst,
                                            int* __restrict__ gh, int e, int nbin) {
    __shared__ int lh[512];
    for (int i = threadIdx.x; i < nbin; i += 256) lh[i] = 0;
    __syncthreads();
    int lo = blockIdx.x * CSR_CHUNK;
    int hi = min(lo + CSR_CHUNK, e);
    for (int i = lo + threadIdx.x; i < hi; i += 256)
        atomicAdd(&lh[dst[i] >> 7], 1);
    __syncthreads();
    for (int i = threadIdx.x; i < nbin; i += 256)
        if (lh[i]) atomicAdd(&gh[i], lh[i]);
}

__global__ __launch_bounds__(512) void k_bscan(
    const int* __restrict__ gh, int* __restrict__ binstart, int* __restrict__ bincur,
    int* __restrict__ rowst, int e, int nbin, int n)
{
    int tid = threadIdx.x, lane = tid & 63, wv = tid >> 6;
    __shared__ int ws[8];
    int x = (tid < nbin) ? gh[tid] : 0;
    int v = x;
#pragma unroll
    for (int off = 1; off < 64; off <<= 1) {
        int t = __shfl_up(v, off, 64);
        if (lane >= off) v += t;
    }
    if (lane == 63) ws[wv] = v;
    __syncthreads();
    if (wv == 0) {
        int w = (lane < 8) ? ws[lane] : 0;
#pragma unroll
        for (int off = 1; off < 8; off <<= 1) {
            int t = __shfl_up(w, off, 64);
            if (lane >= off) w += t;
        }
        if (lane < 8) ws[lane] = w;
    }
    __syncthreads();
    if (wv > 0) v += ws[wv - 1];
    int excl = v - x;
    if (tid < nbin) { binstart[tid] = excl; bincur[tid] = excl; }
    if (tid == 0) { binstart[nbin] = e; rowst[n] = e; }
}

__global__ __launch_bounds__(256) void k_scatter(
    const int* __restrict__ src, const int* __restrict__ dst,
    int* __restrict__ bincur, unsigned* __restrict__ sorted, int e, int nbin)
{
    __shared__ unsigned st[CSR_CHUNK];
    __shared__ int lh[512];
    __shared__ int base[512];
    for (int i = threadIdx.x; i < nbin; i += 256) lh[i] = 0;
    __syncthreads();
    int lo = blockIdx.x * CSR_CHUNK;
    int cnt = min(lo + CSR_CHUNK, e) - lo;
    for (int i = threadIdx.x; i < cnt; i += 256) {
        int d = dst[lo + i], s = src[lo + i];
        st[i] = ((unsigned)d << 16) | (unsigned)s;
        atomicAdd(&lh[d >> 7], 1);
    }
    __syncthreads();
    for (int i = threadIdx.x; i < nbin; i += 256) {
        int c = lh[i];
        base[i] = c ? atomicAdd(&bincur[i], c) : 0;
        lh[i] = 0;
    }
    __syncthreads();
    for (int i = threadIdx.x; i < cnt; i += 256) {
        unsigned u = st[i];
        int b = (int)(u >> 23);
        int r = atomicAdd(&lh[b], 1);
        sorted[base[b] + r] = u;
    }
}

__global__ __launch_bounds__(256) void k_fine(
    const unsigned* __restrict__ sorted, const int* __restrict__ binstart,
    int* __restrict__ rowst, int* __restrict__ csrc, int n)
{
    int b = blockIdx.x;
    int s = binstart[b], t = binstart[b + 1];
    __shared__ int fh[128], fex[128], fcur[128];
    __shared__ int wtot;
    int tid = threadIdx.x;
    if (tid < 128) fh[tid] = 0;
    __syncthreads();
    for (int i = s + tid; i < t; i += 256)
        atomicAdd(&fh[(sorted[i] >> 16) & 127], 1);
    __syncthreads();
    if (tid < 128) {
        int lane = tid & 63;
        int x = fh[tid];
        int v = x;
#pragma unroll
        for (int off = 1; off < 64; off <<= 1) {
            int tv = __shfl_up(v, off, 64);
            if (lane >= off) v += tv;
        }
        fex[tid] = v - x;
        if (tid == 63) wtot = v;
    }
    __syncthreads();
    if (tid >= 64 && tid < 128) fex[tid] += wtot;
    __syncthreads();
    if (tid < 128) {
        int node = b * 128 + tid;
        if (node < n) rowst[node] = s + fex[tid];
        fcur[tid] = 0;
    }
    __syncthreads();
    for (int i = s + tid; i < t; i += 256) {
        unsigned u = sorted[i];
        int d = (u >> 16) & 127;
        int r = atomicAdd(&fcur[d], 1);
        csrc[s + fex[d] + r] = (int)(u & 0xFFFFu);
    }
}

// ---------------- All three W fp16 hi/lo splits in one launch ----------------
__global__ void k_wsplit_all(const float* __restrict__ W1, const float* __restrict__ W2,
                             const float* __restrict__ W3,
                             _Float16* __restrict__ w1h, _Float16* __restrict__ w1l,
                             _Float16* __restrict__ w2h, _Float16* __restrict__ w2l,
                             _Float16* __restrict__ w3h, _Float16* __restrict__ w3l) {
    const int N1 = 128 * 128, N2 = 128 * 128, N3 = 64 * 128;
    for (int i = blockIdx.x * blockDim.x + threadIdx.x; i < N1 + N2 + N3;
         i += gridDim.x * blockDim.x) {
        const float* W; _Float16 *ph, *pl; int j;
        if (i < N1)            { W = W1; ph = w1h; pl = w1l; j = i; }
        else if (i < N1 + N2)  { W = W2; ph = w2h; pl = w2l; j = i - N1; }
        else                   { W = W3; ph = w3h; pl = w3l; j = i - N1 - N2; }
        float v = W[j];
        _Float16 h = (_Float16)v;
        ph[j] = h;
        pl[j] = (_Float16)(v - (float)h);
    }
}

// ---------------- MFMA Linear (fp16 hi/lo W in LDS) + L2-norm prep ----------------
// R12 lesson: this 16-row-per-wave LDS-W form (R10 kernel, 211.7us total) beat
// both the 32-row variant (VGPR 216, occ 8%, 230us) and the register-W
// col-split variant (237us). Keep as-is.
template <int DOUT, bool F32IN>
__global__ __launch_bounds__(256) void k_linear_mfma(
    const void* __restrict__ Xv, const _Float16* __restrict__ Whf,
    const _Float16* __restrict__ Wlf, const float* __restrict__ B,
    _Float16* __restrict__ Hn, float* __restrict__ nrm, float* __restrict__ exself, int n)
{
    constexpr int NT = DOUT / 16;
    __shared__ __align__(16) _Float16 sWh[DOUT * 128];
    __shared__ __align__(16) _Float16 sWl[DOUT * 128];
    const int tid = threadIdx.x;

    for (int i = tid; i < DOUT * 16; i += 256) {
        int row = i >> 4, q = i & 15;
        half8_t vh = *reinterpret_cast<const half8_t*>(Whf + row * 128 + q * 8);
        half8_t vl = *reinterpret_cast<const half8_t*>(Wlf + row * 128 + q * 8);
        int qs = q ^ (row & 15);
        *reinterpret_cast<half8_t*>(&sWh[row * 128 + qs * 8]) = vh;
        *reinterpret_cast<half8_t*>(&sWl[row * 128 + qs * 8]) = vl;
    }
    __syncthreads();

    const int lane = tid & 63;
    const int r16 = lane & 15, kh = lane >> 4;
    const int nw = (n + 15) >> 4;
    const int stride = gridDim.x * 4;
    int wt = blockIdx.x * 4 + (tid >> 6);

    const float* Xf32 = (const float*)Xv;
    const _Float16* Xf16 = (const _Float16*)Xv;

    auto loadX = [&](int group, half8_t a[4]) {
        if (F32IN) {
            const float* px = Xf32 + (size_t)((group << 4) + r16) * 128 + kh * 8;
#pragma unroll
            for (int ks = 0; ks < 4; ks++) {
                float4 xa = *reinterpret_cast<const float4*>(px + ks * 32);
                float4 xb = *reinterpret_cast<const float4*>(px + ks * 32 + 4);
                a[ks] = (half8_t){(_Float16)xa.x, (_Float16)xa.y, (_Float16)xa.z, (_Float16)xa.w,
                                  (_Float16)xb.x, (_Float16)xb.y, (_Float16)xb.z, (_Float16)xb.w};
            }
        } else {
            const _Float16* px = Xf16 + (size_t)((group << 4) + r16) * 128 + kh * 8;
#pragma unroll
            for (int ks = 0; ks < 4; ks++)
                a[ks] = *reinterpret_cast<const half8_t*>(px + ks * 32);
        }
    };

    half8_t a[4];
    if (wt < nw) loadX(wt, a);

    for (; wt < nw; wt += stride) {
        const int rg = wt << 4;
        half8_t nx[4];
        const int wt2 = wt + stride;
        if (wt2 < nw) loadX(wt2, nx);

        f32x4 acc[NT];
#pragma unroll
        for (int t = 0; t < NT; t++) acc[t] = (f32x4){0.f, 0.f, 0.f, 0.f};

#pragma unroll
        for (int ks = 0; ks < 4; ks++) {
            const int qs = (kh + ks * 4) ^ r16;
#pragma unroll
            for (int t = 0; t < NT; t++) {
                const int off = (t * 16 + r16) * 128 + qs * 8;
                half8_t bh = *reinterpret_cast<const half8_t*>(&sWh[off]);
                half8_t bl = *reinterpret_cast<const half8_t*>(&sWl[off]);
                acc[t] = __builtin_amdgcn_mfma_f32_16x16x32_f16(a[ks], bh, acc[t], 0, 0, 0);
                acc[t] = __builtin_amdgcn_mfma_f32_16x16x32_f16(a[ks], bl, acc[t], 0, 0, 0);
            }
        }

        float ss[4] = {0.f, 0.f, 0.f, 0.f};
#pragma unroll
        for (int t = 0; t < NT; t++) {
            float bs = B[t * 16 + r16];
#pragma unroll
            for (int r = 0; r < 4; r++) {
                float v = acc[t][r] + bs;
                acc[t][r] = v;
                ss[r] += v * v;
            }
        }
#pragma unroll
        for (int m = 8; m > 0; m >>= 1) {
#pragma unroll
            for (int r = 0; r < 4; r++) ss[r] += __shfl_xor(ss[r], m, 64);
        }
        float nrmv[4], riv[4];
#pragma unroll
        for (int r = 0; r < 4; r++) {
            nrmv[r] = sqrtf(ss[r]);
            riv[r] = 1.0f / fmaxf(nrmv[r], 1e-12f);
        }
#pragma unroll
        for (int t = 0; t < NT; t++) {
#pragma unroll
            for (int r = 0; r < 4; r++) {
                int grow = rg + kh * 4 + r;
                if (grow < n)
                    Hn[(size_t)grow * DOUT + t * 16 + r16] = (_Float16)(acc[t][r] * riv[r]);
            }
        }
        if (r16 == 0) {
#pragma unroll
            for (int r = 0; r < 4; r++) {
                int grow = rg + kh * 4 + r;
                if (grow < n) {
                    float s = nrmv[r] * riv[r];
                    nrm[grow] = nrmv[r];
                    exself[grow] = __expf(s * s);
                }
            }
        }
#pragma unroll
        for (int ks = 0; ks < 4; ks++) a[ks] = nx[ks];
    }
}

// ---------------- Fused attention aggregation (fp16 rows, SW-pipelined) ----------------
__global__ __launch_bounds__(256) void k_agg128(
    const _Float16* __restrict__ Hn, const float* __restrict__ nrm, const float* __restrict__ exself,
    const int* __restrict__ rowst, const int* __restrict__ csrc,
    _Float16* __restrict__ Oxf, int n)
{
    const int wave = threadIdx.x >> 6, lane = threadIdx.x & 63;
    const int node = blockIdx.x * 4 + wave;
    if (node >= n) return;
    const int g = lane >> 4;
    const int t = lane & 15;

    half8_t hv = *reinterpret_cast<const half8_t*>(Hn + (size_t)node * 128 + t * 8);
    half2_t h2[4];
#pragma unroll
    for (int j = 0; j < 4; j++) h2[j] = (half2_t){hv[2 * j], hv[2 * j + 1]};
    float es = exself[node];
    float esn = es * nrm[node];
    float acc[8];
    float denom;
    if (g == 0) {
#pragma unroll
        for (int j = 0; j < 8; j++) acc[j] = esn * (float)hv[j];
        denom = es;
    } else {
#pragma unroll
        for (int j = 0; j < 8; j++) acc[j] = 0.f;
        denom = 0.f;
    }

    const int p0 = rowst[node], p1 = rowst[node + 1];
    const int nit = (p1 - p0 + 7) >> 3;

    bool vA0 = false, vB0 = false;
    half8_t av0, bv0;
    float nA0 = 0.f, nB0 = 0.f;
    if (nit > 0) {
        int pA = p0 + g, pB = pA + 4;
        vA0 = pA < p1; vB0 = pB < p1;
        int sA = vA0 ? csrc[pA] : node;
        int sB = vB0 ? csrc[pB] : node;
        av0 = *reinterpret_cast<const half8_t*>(Hn + (size_t)sA * 128 + t * 8);
        bv0 = *reinterpret_cast<const half8_t*>(Hn + (size_t)sB * 128 + t * 8);
        nA0 = nrm[sA]; nB0 = nrm[sB];
    }

    for (int k = 0; k < nit; k++) {
        bool vA1 = false, vB1 = false;
        half8_t av1, bv1;
        float nA1 = 0.f, nB1 = 0.f;
        if (k + 1 < nit) {
            int pA = p0 + (k + 1) * 8 + g, pB = pA + 4;
            vA1 = pA < p1; vB1 = pB < p1;
            int sA = vA1 ? csrc[pA] : node;
            int sB = vB1 ? csrc[pB] : node;
            av1 = *reinterpret_cast<const half8_t*>(Hn + (size_t)sA * 128 + t * 8);
            bv1 = *reinterpret_cast<const half8_t*>(Hn + (size_t)sB * 128 + t * 8);
            nA1 = nrm[sA]; nB1 = nrm[sB];
        }

        half2_t da2 = (half2_t){hv[0], hv[1]} * (half2_t){av0[0], av0[1]};
        half2_t db2 = (half2_t){hv[0], hv[1]} * (half2_t){bv0[0], bv0[1]};
#pragma unroll
        for (int j = 1; j < 4; j++) {
            da2 += h2[j] * (half2_t){av0[2 * j], av0[2 * j + 1]};
            db2 += h2[j] * (half2_t){bv0[2 * j], bv0[2 * j + 1]};
        }
        float dA = (float)da2[0] + (float)da2[1];
        float dB = (float)db2[0] + (float)db2[1];
#pragma unroll
        for (int m = 8; m > 0; m >>= 1) {
            dA += __shfl_xor(dA, m, 64);
            dB += __shfl_xor(dB, m, 64);
        }
        float exA = vA0 ? __expf(dA) : 0.f;
        float exB = vB0 ? __expf(dB) : 0.f;
        denom += exA + exB;
        float wA = exA * nA0, wB = exB * nB0;
#pragma unroll
        for (int j = 0; j < 8; j++) acc[j] += wA * (float)av0[j] + wB * (float)bv0[j];

        vA0 = vA1; vB0 = vB1; av0 = av1; bv0 = bv1; nA0 = nA1; nB0 = nB1;
    }

#pragma unroll
    for (int j = 0; j < 8; j++) {
        acc[j] += __shfl_xor(acc[j], 16, 64);
        acc[j] += __shfl_xor(acc[j], 32, 64);
    }
    denom += __shfl_xor(denom, 16, 64);
    denom += __shfl_xor(denom, 32, 64);

    if (g == 0) {
        float inv = 1.0f / denom;
        half8_t o;
#pragma unroll
        for (int j = 0; j < 8; j++)
            o[j] = (_Float16)fmaxf(acc[j] * inv, 0.f);
        *reinterpret_cast<half8_t*>(Oxf + (size_t)node * 128 + t * 8) = o;
    }
}

__global__ __launch_bounds__(256) void k_agg64_lsm(
    const _Float16* __restrict__ Hn, const float* __restrict__ nrm, const float* __restrict__ exself,
    const int* __restrict__ rowst, const int* __restrict__ csrc,
    float* __restrict__ OUT, int n)
{
    const int wave = threadIdx.x >> 6, lane = threadIdx.x & 63;
    const int node = blockIdx.x * 4 + wave;
    if (node >= n) return;
    const int g = lane >> 4;
    const int t = lane & 15;

    half4_t hv = *reinterpret_cast<const half4_t*>(Hn + (size_t)node * 64 + t * 4);
    half2_t h2[2] = {(half2_t){hv[0], hv[1]}, (half2_t){hv[2], hv[3]}};
    float es = exself[node];
    float esn = es * nrm[node];
    float acc[4];
    float denom;
    if (g == 0) {
#pragma unroll
        for (int j = 0; j < 4; j++) acc[j] = esn * (float)hv[j];
        denom = es;
    } else {
        acc[0] = acc[1] = acc[2] = acc[3] = 0.f;
        denom = 0.f;
    }

    const int p0 = rowst[node], p1 = rowst[node + 1];
    const int nit = (p1 - p0 + 7) >> 3;

    bool vA0 = false, vB0 = false;
    half4_t av0, bv0;
    float nA0 = 0.f, nB0 = 0.f;
    if (nit > 0) {
        int pA = p0 + g, pB = pA + 4;
        vA0 = pA < p1; vB0 = pB < p1;
        int sA = vA0 ? csrc[pA] : node;
        int sB = vB0 ? csrc[pB] : node;
        av0 = *reinterpret_cast<const half4_t*>(Hn + (size_t)sA * 64 + t * 4);
        bv0 = *reinterpret_cast<const half4_t*>(Hn + (size_t)sB * 64 + t * 4);
        nA0 = nrm[sA]; nB0 = nrm[sB];
    }

    for (int k = 0; k < nit; k++) {
        bool vA1 = false, vB1 = false;
        half4_t av1, bv1;
        float nA1 = 0.f, nB1 = 0.f;
        if (k + 1 < nit) {
            int pA = p0 + (k + 1) * 8 + g, pB = pA + 4;
            vA1 = pA < p1; vB1 = pB < p1;
            int sA = vA1 ? csrc[pA] : node;
            int sB = vB1 ? csrc[pB] : node;
            av1 = *reinterpret_cast<const half4_t*>(Hn + (size_t)sA * 64 + t * 4);
            bv1 = *reinterpret_cast<const half4_t*>(Hn + (size_t)sB * 64 + t * 4);
            nA1 = nrm[sA]; nB1 = nrm[sB];
        }

        half2_t da2 = h2[0] * (half2_t){av0[0], av0[1]};
        half2_t db2 = h2[0] * (half2_t){bv0[0], bv0[1]};
        da2 += h2[1] * (half2_t){av0[2], av0[3]};
        db2 += h2[1] * (half2_t){bv0[2], bv0[3]};
        float dA = (float)da2[0] + (float)da2[1];
        float dB = (float)db2[0] + (float)db2[1];
#pragma unroll
        for (int m = 8; m > 0; m >>= 1) {
            dA += __shfl_xor(dA, m, 64);
            dB += __shfl_xor(dB, m, 64);
        }
        float exA = vA0 ? __expf(dA) : 0.f;
        float exB = vB0 ? __expf(dB) : 0.f;
        denom += exA + exB;
        float wA = exA * nA0, wB = exB * nB0;
#pragma unroll
        for (int j = 0; j < 4; j++) acc[j] += wA * (float)av0[j] + wB * (float)bv0[j];

        vA0 = vA1; vB0 = vB1; av0 = av1; bv0 = bv1; nA0 = nA1; nB0 = nB1;
    }

#pragma unroll
    for (int j = 0; j < 4; j++) {
        acc[j] += __shfl_xor(acc[j], 16, 64);
        acc[j] += __shfl_xor(acc[j], 32, 64);
    }
    denom += __shfl_xor(denom, 16, 64);
    denom += __shfl_xor(denom, 32, 64);

    float inv = 1.0f / denom;
    float v0 = acc[0] * inv, v1 = acc[1] * inv, v2 = acc[2] * inv, v3 = acc[3] * inv;
    float mx = fmaxf(fmaxf(v0, v1), fmaxf(v2, v3));
#pragma unroll
    for (int m = 8; m > 0; m >>= 1) mx = fmaxf(mx, __shfl_xor(mx, m, 64));
    float se = __expf(v0 - mx) + __expf(v1 - mx) + __expf(v2 - mx) + __expf(v3 - mx);
#pragma unroll
    for (int m = 8; m > 0; m >>= 1) se += __shfl_xor(se, m, 64);
    float lse = mx + logf(se);
    if (g == 0) {
        float* op = OUT + (size_t)node * 64 + t * 4;
        *reinterpret_cast<float4*>(op) = make_float4(v0 - lse, v1 - lse, v2 - lse, v3 - lse);
    }
}

extern "C" void kernel_launch(void* const* d_in, const int* in_sizes, int n_in,
                              void* d_out, int out_size, void* d_ws, size_t ws_size,
                              hipStream_t stream)
{
    const float* x  = (const float*)d_in[0];
    const int*   ei = (const int*)d_in[1];
    const float* W1 = (const float*)d_in[2];
    const float* b1 = (const float*)d_in[3];
    const float* W2 = (const float*)d_in[4];
    const float* b2 = (const float*)d_in[5];
    const float* W3 = (const float*)d_in[6];
    const float* b3 = (const float*)d_in[7];
    float* out = (float*)d_out;

    const int n = in_sizes[0] / 128;
    const int e = in_sizes[1] / 2;
    const int* esrc = ei;
    const int* edst = ei + e;
    const int npad = (n + 15) & ~15;

    uintptr_t wp = ((uintptr_t)d_ws + 15) & ~(uintptr_t)15;
#define CARVE(ty, name, count) ty* name = (ty*)wp; wp = (wp + (size_t)(count) * sizeof(ty) + 15) & ~(uintptr_t)15
    CARVE(_Float16, xf, (size_t)npad * 128);
    CARVE(_Float16, hn16, (size_t)npad * 128);
    CARVE(float, nrm, n);
    CARVE(float, exs, n);
    CARVE(int, rowst, n + 1);
    CARVE(int, gh, 512);
    CARVE(int, binstart, 513);
    CARVE(int, bincur, 512);
    CARVE(unsigned, sorted, e);
    CARVE(int, csrc, e);
    CARVE(_Float16, w1h, 128 * 128);
    CARVE(_Float16, w1l, 128 * 128);
    CARVE(_Float16, w2h, 128 * 128);
    CARVE(_Float16, w2l, 128 * 128);
    CARVE(_Float16, w3h, 64 * 128);
    CARVE(_Float16, w3l, 64 * 128);
#undef CARVE

    const int nbin = (n + 127) >> 7;
    const int nchunk = (e + CSR_CHUNK - 1) / CSR_CHUNK;

    hipMemsetAsync(gh, 0, 512 * sizeof(int), stream);
    k_bh<<<nchunk, 256, 0, stream>>>(edst, gh, e, nbin);
    k_bscan<<<1, 512, 0, stream>>>(gh, binstart, bincur, rowst, e, nbin, n);
    k_scatter<<<nchunk, 256, 0, stream>>>(esrc, edst, bincur, sorted, e, nbin);
    k_fine<<<nbin, 256, 0, stream>>>(sorted, binstart, rowst, csrc, n);
    k_wsplit_all<<<160, 256, 0, stream>>>(W1, W2, W3, w1h, w1l, w2h, w2l, w3h, w3l);

    const int lgrid = 512;
    const int agrid = (n + 3) / 4;

    k_linear_mfma<128, true><<<lgrid, 256, 0, stream>>>(x, w1h, w1l, b1, hn16, nrm, exs, n);
    k_agg128<<<agrid, 256, 0, stream>>>(hn16, nrm, exs, rowst, csrc, xf, n);
    k_linear_mfma<128, false><<<lgrid, 256, 0, stream>>>(xf, w2h, w2l, b2, hn16, nrm, exs, n);
    k_agg128<<<agrid, 256, 0, stream>>>(hn16, nrm, exs, rowst, csrc, xf, n);
    k_linear_mfma<64, false><<<lgrid, 256, 0, stream>>>(xf, w3h, w3l, b3, hn16, nrm, exs, n);
    k_agg64_lsm<<<agrid, 256, 0, stream>>>(hn16, nrm, exs, rowst, csrc, out, n);
}